// Round 15
// baseline (285.787 us; speedup 1.0000x reference)
//
#include <hip/hip_runtime.h>

#define B_   4
#define C_   256
#define C2_  128
#define HIN  128
#define HO   63
#define NSEQ 3969          // 63*63
#define NPAD 4032          // 63*64
#define QPAD 4096
#define D_   128
#define TOT  (B_*C_*NSEQ)  // 4064256
#define SPLITS 4

typedef _Float16 f16x8 __attribute__((ext_vector_type(8)));
typedef _Float16 f16x2 __attribute__((ext_vector_type(2)));
typedef short    s16x8 __attribute__((ext_vector_type(8)));
typedef float    f32x4 __attribute__((ext_vector_type(4)));
typedef unsigned short u16;
typedef u16 u16x8 __attribute__((ext_vector_type(8)));
typedef unsigned u32x2 __attribute__((ext_vector_type(2)));

#define MFMA16(a,b,c) __builtin_amdgcn_mfma_f32_16x16x32_f16((a),(b),(c),0,0,0)
#define MFMABF(a,b,c) __builtin_amdgcn_mfma_f32_16x16x32_bf16((a),(b),(c),0,0,0)

__device__ __forceinline__ float b2f(u16 u) {
  unsigned v = ((unsigned)u) << 16;
  return __builtin_bit_cast(float, v);
}
__device__ __forceinline__ u16 f2b(float f) {   // RTN-even
  unsigned u = __builtin_bit_cast(unsigned, f);
  return (u16)((u + 0x7FFFu + ((u >> 16) & 1u)) >> 16);
}
__device__ __forceinline__ float h2f(u16 u) {   // f16 bits -> float
  return (float)__builtin_bit_cast(_Float16, u);
}
__device__ __forceinline__ unsigned packhl(float v) {  // f16 hi/lo split -> u32
  _Float16 hx = (_Float16)v;
  _Float16 lx = (_Float16)(v - (float)hx);
  return (unsigned)__builtin_bit_cast(u16, hx) |
         ((unsigned)__builtin_bit_cast(u16, lx) << 16);
}

template<int CTRL>
__device__ __forceinline__ float dppf(float x) {
  return __builtin_bit_cast(float,
      __builtin_amdgcn_mov_dpp(__builtin_bit_cast(int, x), CTRL, 0xF, 0xF, true));
}
__device__ __forceinline__ float rmax16(float x) {
  x = fmaxf(x, dppf<0xB1>(x));
  x = fmaxf(x, dppf<0x4E>(x));
  x = fmaxf(x, dppf<0x124>(x));
  x = fmaxf(x, dppf<0x128>(x));
  return x;
}
__device__ __forceinline__ float rsum16(float x) {
  x += dppf<0xB1>(x);
  x += dppf<0x4E>(x);
  x += dppf<0x124>(x);
  x += dppf<0x128>(x);
  return x;
}

// ========== pool_k: maxpool 3x3/s2 + transpose + bf16 hi/lo split ==========
// xp stored f16 (residual only; values <= ~5, err ~2^-11 rel)
__global__ __launch_bounds__(256) void pool_k(
    const float* __restrict__ x, _Float16* __restrict__ xp, u16* __restrict__ xpT2,
    u16* __restrict__ W2, const float* __restrict__ tw, const float* __restrict__ pw,
    const float* __restrict__ gw, float* gsum, float* gsq) {
  __shared__ unsigned Tls[64 * 69];
  int h = blockIdx.x, cg = blockIdx.y, b = blockIdx.z;
  int tid = threadIdx.x;
  if (cg == 4) {                       // weight split (252 blocks, need 192)
    if (h == 0 && b == 0) { gsum[tid] = 0.f; gsq[tid] = 0.f; }
    int base = ((b * 63 + h) * 256 + tid) * 2;
#pragma unroll
    for (int e2 = 0; e2 < 2; e2++) {
      int e = base + e2;
      if (e < 3 * 128 * 256) {
        int mat = e >> 15, idx = e & 32767;
        int oc = idx >> 8, k = idx & 255;
        const float* W = (mat == 0) ? tw : (mat == 1) ? pw : gw;
        float v = W[oc * 256 + k];
        u16 hi = f2b(v);
        u16 lo = f2b(v - b2f(hi));
        W2[((long)(mat * 128 + oc)) * 512 + 2 * k]     = hi;
        W2[((long)(mat * 128 + oc)) * 512 + 2 * k + 1] = lo;
      }
    }
    return;
  }
  int cl = tid >> 2, w0 = (tid & 3) << 4;   // 64 channels x 4 w-groups of 16
  int c = cg * 64 + cl;
  long rowbase = ((long)(b * C_ + c) * HIN + 2 * h) * HIN + 2 * w0;
  float best[16];
#pragma unroll
  for (int j = 0; j < 16; j++) best[j] = -3e38f;
#pragma unroll
  for (int dh = 0; dh < 3; dh++) {
    long ro = rowbase + dh * HIN;
    float v[40];
#pragma unroll
    for (int ch = 0; ch < 10; ch++) {
      f32x4 a = *(const f32x4*)(x + ro + ch * 4);
#pragma unroll
      for (int j = 0; j < 4; j++) v[ch * 4 + j] = a[j];
    }
#pragma unroll
    for (int j = 0; j < 16; j++)
      best[j] = fmaxf(best[j], fmaxf(fmaxf(v[2 * j], v[2 * j + 1]), v[2 * j + 2]));
  }
  long xo = (long)(b * C_ + c) * NPAD + h * HO + w0;
#pragma unroll
  for (int j = 0; j < 16; j++)
    if (w0 + j < HO) xp[xo + j] = (_Float16)best[j];
#pragma unroll
  for (int j = 0; j < 16; j++) {
    u16 hi = f2b(best[j]);
    u16 lo = f2b(best[j] - b2f(hi));
    Tls[cl * 69 + w0 + j] = (unsigned)hi | ((unsigned)lo << 16);
  }
  __syncthreads();
  int w = tid >> 2, cc0 = (tid & 3) << 4;   // 64 w x 4 c-groups of 16
  if (w < HO) {
    int p = h * HO + w;
    u16 outv[32];
#pragma unroll
    for (int j = 0; j < 16; j++) {
      unsigned word = Tls[(cc0 + j) * 69 + w];
      outv[2 * j]     = (u16)(word & 0xFFFF);
      outv[2 * j + 1] = (u16)(word >> 16);
    }
    u16* d = xpT2 + ((long)b * NPAD + p) * 512 + 2 * (cg * 64 + cc0);
#pragma unroll
    for (int q = 0; q < 4; q++)
      *(u16x8*)(d + q * 8) = *(u16x8*)&outv[q * 8];
  }
}

// ========== qkv_k: K=512 bf16-split MFMA GEMM, XCD-grouped blocks ==========
__global__ __launch_bounds__(256) void qkv_k(
    const u16* __restrict__ xpT2, const u16* __restrict__ W2,
    _Float16* Qh, _Float16* Ql, _Float16* Kv, _Float16* Vt) {
  __shared__ u16 Asm[64 * 256];       // 32 KB, XOR-swizzled 16B chunks
  __shared__ u16 Bsm[64 * 256];       // 32 KB
  __shared__ float Tsm[4][16][64];    // 16 KB
  int x = blockIdx.x;
  int y = (x % 48) >> 3;              // 0..5
  int g = (x & 7) + ((x / 48) << 3);  // (pt,b) group, same-XCD for all y
  if (g >= 252) return;
  int pt = g % 63, b = g / 63;
  int tid = threadIdx.x, wave = tid >> 6, lane = tid & 63;
  int quad = lane >> 4, l16 = lane & 15;
  int mat = y >> 1, half = y & 1;
  const u16* Wr = W2 + ((long)(mat * 128 + half * 64)) * 512;
  const u16* Xb = xpT2 + ((long)b * NPAD + pt * 64) * 512;
  f32x4 acc[4];
#pragma unroll
  for (int s = 0; s < 4; s++) acc[s] = (f32x4){0.f, 0.f, 0.f, 0.f};
#pragma unroll
  for (int ck = 0; ck < 2; ck++) {    // two 256-wide K chunks of 512
    if (ck) __syncthreads();
#pragma unroll
    for (int i = 0; i < 8; i++) {
      int g2 = tid + i * 256;         // 0..2047
      int r = g2 >> 5, ccc = g2 & 31;
      int sw = (ccc ^ (r & 15)) << 3;
      *(u16x8*)&Asm[r * 256 + sw] = *(const u16x8*)(Wr + (long)r * 512 + ck * 256 + ccc * 8);
      *(u16x8*)&Bsm[r * 256 + sw] = *(const u16x8*)(Xb + (long)r * 512 + ck * 256 + ccc * 8);
    }
    __syncthreads();
#pragma unroll
    for (int kc = 0; kc < 8; kc++) {
      s16x8 a = *(const s16x8*)&Asm[(wave * 16 + l16) * 256 + (((kc * 4 + quad) ^ l16) << 3)];
#pragma unroll
      for (int s = 0; s < 4; s++) {
        s16x8 bv = *(const s16x8*)&Bsm[(s * 16 + l16) * 256 + (((kc * 4 + quad) ^ l16) << 3)];
        acc[s] = MFMABF(a, bv, acc[s]);
      }
    }
  }
  int chanb = half * 64 + wave * 16;
  if (mat == 2) {
    _Float16* dv = Vt + (long)b * C2_ * NPAD;
#pragma unroll
    for (int s = 0; s < 4; s++)
#pragma unroll
      for (int r = 0; r < 4; r++) {
        int p = pt * 64 + s * 16 + l16;
        if (p < NSEQ) dv[(long)(chanb + quad * 4 + r) * NPAD + p] = (_Float16)acc[s][r];
      }
  } else {
#pragma unroll
    for (int s = 0; s < 4; s++)
#pragma unroll
      for (int r = 0; r < 4; r++)
        Tsm[wave][quad * 4 + r][s * 16 + l16] = acc[s][r];
    int p = pt * 64 + lane;           // wave-local LDS roundtrip, no barrier
    if (p < NSEQ) {
      f16x8 hv[2], lv[2];
#pragma unroll
      for (int cl2 = 0; cl2 < 16; cl2++) {
        float v = Tsm[wave][cl2][lane];
        _Float16 hx = (_Float16)v;
        hv[cl2 >> 3][cl2 & 7] = hx;
        lv[cl2 >> 3][cl2 & 7] = (_Float16)(v - (float)hx);
      }
      if (mat == 0) {
        _Float16* dh = Qh + ((long)b * QPAD + p) * 128 + chanb;
        _Float16* dl = Ql + ((long)b * QPAD + p) * 128 + chanb;
        *(f16x8*)dh = hv[0]; *(f16x8*)(dh + 8) = hv[1];
        *(f16x8*)dl = lv[0]; *(f16x8*)(dl + 8) = lv[1];
      } else {
        _Float16* dk = Kv + ((long)b * NPAD + p) * 128 + chanb;
        *(f16x8*)dk = hv[0]; *(f16x8*)(dk + 8) = hv[1];
      }
    }
  }
}

// ========== flash v14 (R14-proven): XCD-grouped splits, f16 Opart ==========
__global__ __launch_bounds__(256, 3) void flash_k(
    const _Float16* __restrict__ Qh, const _Float16* __restrict__ Ql,
    const _Float16* __restrict__ Kv, const _Float16* __restrict__ Vt,
    _Float16* __restrict__ Opart, float* __restrict__ Mp, float* __restrict__ Lp) {
  __shared__ _Float16 Ks[64 * 128];   // 16 KB
  __shared__ _Float16 Vs[128 * 64];   // 16 KB
  __shared__ _Float16 Ps[4 * 640];    // 5 KB: per-wave 16x40-padded half-tile
  int x = blockIdx.x;
  int split = (x % 32) >> 3;          // 0..3
  int g = (x & 7) + ((x / 32) << 3);  // (qt,b) group, same-XCD for all splits
  if (g >= 252) return;
  int qt = g % 63, b = g / 63;
  int tid = threadIdx.x, wave = tid >> 6, lane = tid & 63;
  int quad = lane >> 4, l16 = lane & 15;
  const _Float16* Qhb = Qh + (long)b * QPAD * D_;
  const _Float16* Qlb = Ql + (long)b * QPAD * D_;
  const _Float16* Kb  = Kv + (long)b * NPAD * D_;
  const _Float16* Vb  = Vt + (long)b * C2_ * NPAD;

  long qrow = qt * 64 + wave * 16 + l16;
  f16x8 aqh[4], aql[4];
#pragma unroll
  for (int kk = 0; kk < 4; kk++) {
    aqh[kk] = *(const f16x8*)(Qhb + qrow * D_ + kk * 32 + quad * 8);
    aql[kk] = *(const f16x8*)(Qlb + qrow * D_ + kk * 32 + quad * 8);
  }
  f32x4 o_acc[8];
#pragma unroll
  for (int s = 0; s < 8; s++) o_acc[s] = (f32x4){0.f, 0.f, 0.f, 0.f};
  float m_r[4] = {-3e38f, -3e38f, -3e38f, -3e38f};
  float l_r[4] = {0.f, 0.f, 0.f, 0.f};
  const float LOG2E = 1.4426950408889634f;
  int po = wave * 640;
  int t0 = split * 16;
  int t1 = (t0 + 16 < 63) ? (t0 + 16) : 63;   // splits: 16,16,16,15

  int rK = tid >> 4, qK = tid & 15;
  int cV = tid >> 3, qV = tid & 7;
  const _Float16* Kg = Kb + rK * D_ + qK * 8;              // + t*8192 + i*2048
  const _Float16* Vg = Vb + (long)cV * NPAD + qV * 8;      // + t*64 + i*32*NPAD
  int lk = rK * 128 + ((qK ^ (rK & 15)) << 3);             // + i*2048
  int lv = cV * 64 + ((qV ^ (cV & 7)) << 3);               // + i*2048

  f16x8 pk0, pk1, pk2, pk3, pv0, pv1, pv2, pv3;
  {
    long ko = (long)t0 * 8192;
    pk0 = *(const f16x8*)(Kg + ko);
    pk1 = *(const f16x8*)(Kg + ko + 2048);
    pk2 = *(const f16x8*)(Kg + ko + 4096);
    pk3 = *(const f16x8*)(Kg + ko + 6144);
    int vo = t0 * 64;
    pv0 = *(const f16x8*)(Vg + vo);
    pv1 = *(const f16x8*)(Vg + vo + (long)32 * NPAD);
    pv2 = *(const f16x8*)(Vg + vo + (long)64 * NPAD);
    pv3 = *(const f16x8*)(Vg + vo + (long)96 * NPAD);
  }

#pragma unroll 1
  for (int t = t0; t < t1; t++) {
    __syncthreads();                  // (A) prior tile's Ks/Vs reads done
    *(f16x8*)&Ks[lk]        = pk0;
    *(f16x8*)&Ks[lk + 2048] = pk1;
    *(f16x8*)&Ks[lk + 4096] = pk2;
    *(f16x8*)&Ks[lk + 6144] = pk3;
    *(f16x8*)&Vs[lv]        = pv0;
    *(f16x8*)&Vs[lv + 2048] = pv1;
    *(f16x8*)&Vs[lv + 4096] = pv2;
    *(f16x8*)&Vs[lv + 6144] = pv3;
    __syncthreads();                  // (B) tiles visible
    if (t + 1 < t1) {                 // issue next tile a full phase early
      long ko = (long)(t + 1) * 8192;
      pk0 = *(const f16x8*)(Kg + ko);
      pk1 = *(const f16x8*)(Kg + ko + 2048);
      pk2 = *(const f16x8*)(Kg + ko + 4096);
      pk3 = *(const f16x8*)(Kg + ko + 6144);
      int vo = (t + 1) * 64;
      pv0 = *(const f16x8*)(Vg + vo);
      pv1 = *(const f16x8*)(Vg + vo + (long)32 * NPAD);
      pv2 = *(const f16x8*)(Vg + vo + (long)64 * NPAD);
      pv3 = *(const f16x8*)(Vg + vo + (long)96 * NPAD);
    }

    f32x4 s_acc[4];
#pragma unroll
    for (int s = 0; s < 4; s++) s_acc[s] = (f32x4){0.f, 0.f, 0.f, 0.f};
    __builtin_amdgcn_s_setprio(1);
#pragma unroll
    for (int kk = 0; kk < 4; kk++) {
      f16x8 bh[4];
#pragma unroll
      for (int s = 0; s < 4; s++)
        bh[s] = *(const f16x8*)&Ks[(s * 16 + l16) * 128 + (((kk * 4 + quad) ^ l16) << 3)];
#pragma unroll
      for (int s = 0; s < 4; s++) s_acc[s] = MFMA16(aqh[kk], bh[s], s_acc[s]);
#pragma unroll
      for (int s = 0; s < 4; s++) s_acc[s] = MFMA16(aql[kk], bh[s], s_acc[s]);
    }
    __builtin_amdgcn_s_setprio(0);

    if (t == 62) {                    // only the last K-tile has invalid cols
#pragma unroll
      for (int s = 0; s < 4; s++) {
        if (t * 64 + s * 16 + l16 >= NSEQ) {
#pragma unroll
          for (int r = 0; r < 4; r++) s_acc[s][r] = -3e38f;
        }
      }
    }
    float mx[4];
#pragma unroll
    for (int r = 0; r < 4; r++) {
      mx[r] = fmaxf(fmaxf(s_acc[0][r], s_acc[1][r]), fmaxf(s_acc[2][r], s_acc[3][r]));
      mx[r] = rmax16(mx[r]);
    }
    // defer-max: only rescale when the running max grows by >8
    bool need = false;
#pragma unroll
    for (int r = 0; r < 4; r++) need = need || (mx[r] > m_r[r] + 8.0f);
    if (__any(need)) {
      float alpha[4];
#pragma unroll
      for (int r = 0; r < 4; r++) {
        float mn = fmaxf(m_r[r], mx[r]);
        alpha[r] = exp2f((m_r[r] - mn) * LOG2E);
        m_r[r] = mn;
        l_r[r] *= alpha[r];
      }
#pragma unroll
      for (int s8 = 0; s8 < 8; s8++)
#pragma unroll
        for (int r = 0; r < 4; r++) o_acc[s8][r] *= alpha[r];
    }
    float rs[4] = {0.f, 0.f, 0.f, 0.f};
    // phase A: P k-cols 0..31 (s=0,1) -> padded half-buffer [q=m][k]
#pragma unroll
    for (int s = 0; s < 2; s++)
#pragma unroll
      for (int r = 0; r < 4; r++) {
        float p = exp2f((s_acc[s][r] - m_r[r]) * LOG2E);
        rs[r] += p;
        int m = quad * 4 + r;
        Ps[po + m * 40 + s * 16 + l16] = (_Float16)p;
      }
    f16x8 ap0 = *(const f16x8*)&Ps[po + l16 * 40 + quad * 8];
    // phase B: P k-cols 32..63 overwrite same region (in-wave DS order)
#pragma unroll
    for (int s = 2; s < 4; s++)
#pragma unroll
      for (int r = 0; r < 4; r++) {
        float p = exp2f((s_acc[s][r] - m_r[r]) * LOG2E);
        rs[r] += p;
        int m = quad * 4 + r;
        Ps[po + m * 40 + (s - 2) * 16 + l16] = (_Float16)p;
      }
    f16x8 ap1 = *(const f16x8*)&Ps[po + l16 * 40 + quad * 8];
#pragma unroll
    for (int r = 0; r < 4; r++) {
      rs[r] = rsum16(rs[r]);
      l_r[r] += rs[r];
    }
    __builtin_amdgcn_s_setprio(1);
#pragma unroll
    for (int s8 = 0; s8 < 8; s8++) {
      int c2 = s8 * 16 + l16;
      f16x8 bv = *(const f16x8*)&Vs[c2 * 64 + ((quad ^ (c2 & 7)) << 3)];
      o_acc[s8] = MFMA16(ap0, bv, o_acc[s8]);
    }
#pragma unroll
    for (int s8 = 0; s8 < 8; s8++) {
      int c2 = s8 * 16 + l16;
      f16x8 bv = *(const f16x8*)&Vs[c2 * 64 + (((4 + quad) ^ (c2 & 7)) << 3)];
      o_acc[s8] = MFMA16(ap1, bv, o_acc[s8]);
    }
    __builtin_amdgcn_s_setprio(0);
  }

  _Float16* Ob = Opart + (long)(b * SPLITS + split) * NSEQ * D_;
  float* Mb = Mp + (long)(b * SPLITS + split) * NSEQ;
  float* Lb = Lp + (long)(b * SPLITS + split) * NSEQ;
#pragma unroll
  for (int r = 0; r < 4; r++) {
    int n = qt * 64 + wave * 16 + quad * 4 + r;
    if (n < NSEQ) {
#pragma unroll
      for (int s8 = 0; s8 < 8; s8++)
        Ob[(long)n * D_ + s8 * 16 + l16] = (_Float16)o_acc[s8][r];
      if (l16 == 0) { Mb[n] = m_r[r]; Lb[n] = l_r[r]; }
    }
  }
}

// ========== out_k v6: fused merge + y_w MFMA GEMM + BN stats ==========
// Key identity: Opart's linear index n*128+d == flat raw-view index
// c2*NSEQ + p. A 64-wide p-span crosses <=1 row boundary, so each c2 needs
// weights for n0(c2) and n0+1 only -> 256-slot LDS table. merge_k deleted.
__global__ __launch_bounds__(256) void out_k(const _Float16* __restrict__ Opart,
                                             const float* __restrict__ Mp,
                                             const float* __restrict__ Lp,
                                             const float* __restrict__ yw,
                                             unsigned* __restrict__ outp,
                                             float* gsum, float* gsumsq) {
  __shared__ u16 Asm2[64 * 256];   // w tile, rows c_out, k-interleaved hi/lo
  __shared__ u16 Bsm2[64 * 256];   // merged-y tile, rows p, k-interleaved hi/lo
  __shared__ float Wtab[256][4];   // slot = c2*2 + delta; w_s/den per n
  int x = blockIdx.x;
  int ct = (x % 32) >> 3;             // 0..3
  int g = (x & 7) + ((x / 32) << 3);
  if (g >= 252) return;
  int pt = g % 63, b = g / 63;
  int tid = threadIdx.x, wave = tid >> 6, lane = tid & 63;
  int quad = lane >> 4, l16 = lane & 15;
  int p0 = pt * 64;
  const float LOG2E = 1.4426950408889634f;
  const long SSTR = (long)NSEQ * D_;  // split stride in Opart
  const _Float16* O0 = Opart + (long)b * SPLITS * SSTR;

  // ---- merge-weight table: each thread owns one (c2, delta) slot ----
  {
    int c2 = tid >> 1, dlt = tid & 1;
    int n = ((c2 * NSEQ + p0) >> 7) + dlt;
    float w0 = 0.f, w1 = 0.f, w2 = 0.f, w3 = 0.f;
    if (n < NSEQ) {
      float m0 = Mp[(long)(b * SPLITS + 0) * NSEQ + n];
      float m1 = Mp[(long)(b * SPLITS + 1) * NSEQ + n];
      float m2 = Mp[(long)(b * SPLITS + 2) * NSEQ + n];
      float m3 = Mp[(long)(b * SPLITS + 3) * NSEQ + n];
      float m = fmaxf(fmaxf(m0, m1), fmaxf(m2, m3));
      w0 = exp2f((m0 - m) * LOG2E);
      w1 = exp2f((m1 - m) * LOG2E);
      w2 = exp2f((m2 - m) * LOG2E);
      w3 = exp2f((m3 - m) * LOG2E);
      float den = w0 * Lp[(long)(b * SPLITS + 0) * NSEQ + n]
                + w1 * Lp[(long)(b * SPLITS + 1) * NSEQ + n]
                + w2 * Lp[(long)(b * SPLITS + 2) * NSEQ + n]
                + w3 * Lp[(long)(b * SPLITS + 3) * NSEQ + n];
      float inv = 1.f / den;
      w0 *= inv; w1 *= inv; w2 *= inv; w3 *= inv;
    }
    Wtab[tid][0] = w0; Wtab[tid][1] = w1; Wtab[tid][2] = w2; Wtab[tid][3] = w3;
  }
  __syncthreads();

#pragma unroll
  for (int i = 0; i < 8; i++) {
    int g2 = tid + i * 256;
    // W: r = c_out row (0..63), ccc = 4-float chunk (0..31)
    int r = g2 >> 5, ccc = g2 & 31;
    f32x4 w4 = *(const f32x4*)(yw + (ct * 64 + r) * C2_ + ccc * 4);
    u16 tw2[8];
#pragma unroll
    for (int j = 0; j < 4; j++) {
      unsigned wp = packhl(w4[j]);
      tw2[2 * j]     = (u16)(wp & 0xFFFF);
      tw2[2 * j + 1] = (u16)(wp >> 16);
    }
    *(u16x8*)&Asm2[r * 256 + ((ccc ^ (r & 15)) << 3)] = *(u16x8*)tw2;
    // merged Y (raw view): element (c2, p) = flat y[c2*NSEQ + p0 + p]
    int p = g2 & 63, c4 = g2 >> 6;
    u16 ty[8];
    bool ok = (p0 + p) < NSEQ;
#pragma unroll
    for (int j = 0; j < 4; j++) {
      int c2 = c4 * 4 + j;
      float mv = 0.f;
      if (ok) {
        int base = c2 * NSEQ + p0;
        int flat = base + p;
        int slot = c2 * 2 + ((flat >> 7) - (base >> 7));
        mv = Wtab[slot][0] * (float)O0[flat]
           + Wtab[slot][1] * (float)O0[flat + SSTR]
           + Wtab[slot][2] * (float)O0[flat + 2 * SSTR]
           + Wtab[slot][3] * (float)O0[flat + 3 * SSTR];
      }
      unsigned wp = packhl(mv);
      ty[2 * j]     = (u16)(wp & 0xFFFF);
      ty[2 * j + 1] = (u16)(wp >> 16);
    }
    *(u16x8*)&Bsm2[p * 256 + ((c4 ^ (p & 15)) << 3)] = *(u16x8*)ty;
  }
  __syncthreads();
  f32x4 acc[4];
#pragma unroll
  for (int s = 0; s < 4; s++) acc[s] = (f32x4){0.f, 0.f, 0.f, 0.f};
#pragma unroll
  for (int kc = 0; kc < 8; kc++) {
    f16x8 a = *(const f16x8*)&Asm2[(wave * 16 + l16) * 256 + (((kc * 4 + quad) ^ l16) << 3)];
#pragma unroll
    for (int s = 0; s < 4; s++) {
      f16x8 bv = *(const f16x8*)&Bsm2[(s * 16 + l16) * 256 + (((kc * 4 + quad) ^ l16) << 3)];
      acc[s] = MFMA16(a, bv, acc[s]);
    }
  }
  long ob = ((long)b * C_ + ct * 64 + wave * 16) * NSEQ;
#pragma unroll
  for (int r = 0; r < 4; r++) {
    int row = quad * 4 + r;
    float s1 = 0.f, s2 = 0.f;
#pragma unroll
    for (int s = 0; s < 4; s++) {
      int p = p0 + s * 16 + l16;
      float v = acc[s][r];
      if (p < NSEQ) {
        outp[ob + (long)row * NSEQ + p] = packhl(v);
        s1 += v;
        s2 += v * v;
      }
    }
    s1 = rsum16(s1);
    s2 = rsum16(s2);
    if (l16 == 0) {
      atomicAdd(gsum + ct * 64 + wave * 16 + row, s1);
      atomicAdd(gsumsq + ct * 64 + wave * 16 + row, s2);
    }
  }
}

// ========== BN (training) + residual + relu, packed input, f16 residual ==========
__global__ __launch_bounds__(256) void bn_k(const unsigned* __restrict__ outp,
                                            const float* gsum, const float* gsumsq,
                                            const float* __restrict__ bnw,
                                            const float* __restrict__ bnb,
                                            const _Float16* __restrict__ xp, float* out) {
  int idx = blockIdx.x * 256 + threadIdx.x;
  if (idx >= TOT) return;
  int p = idx % NSEQ;
  int bc = idx / NSEQ;
  int c = bc & (C_ - 1);
  const float invn = 1.0f / (float)(B_ * NSEQ);
  float mean = gsum[c] * invn;
  float var = gsumsq[c] * invn - mean * mean;
  var = fmaxf(var, 0.f);
  float is = rsqrtf(var + 1e-5f);
  unsigned w = outp[idx];
  float ov = h2f((u16)(w & 0xFFFF)) + h2f((u16)(w >> 16));
  float v = (ov - mean) * is * bnw[c] + bnb[c] + (float)xp[(long)bc * NPAD + p];
  out[idx] = fmaxf(v, 0.f);
}

// ========== launcher (5 graph nodes) ==========
extern "C" void kernel_launch(void* const* d_in, const int* in_sizes, int n_in,
                              void* d_out, int out_size, void* d_ws, size_t ws_size,
                              hipStream_t stream) {
  size_t off = 0;
  auto alloc = [&](size_t bytes) -> char* {
    char* p = (char*)d_ws + off;
    off += (bytes + 255) & ~(size_t)255;
    return p;
  };
  _Float16* xp   = (_Float16*)alloc(2 * (size_t)B_ * C_ * NPAD);            // 8.25 MB (f16)
  u16*      xpT2 = (u16*)alloc(2 * (size_t)B_ * NPAD * 512);                // 16.5 MB (Mp/Lp later)
  u16*      W2   = (u16*)alloc(2 * (size_t)3 * 128 * 512);                  // 384 KB
  _Float16* Qh   = (_Float16*)alloc(2 * (size_t)B_ * QPAD * D_);            // 4.2 MB
  _Float16* Ql   = (_Float16*)alloc(2 * (size_t)B_ * QPAD * D_);            // 4.2 MB
  _Float16* Kv   = (_Float16*)alloc(2 * (size_t)B_ * NPAD * D_);            // 4.1 MB (outp later)
  _Float16* Vt   = (_Float16*)alloc(2 * (size_t)B_ * C2_ * NPAD);           // 4.1 MB
  _Float16* big  = (_Float16*)alloc(2 * (size_t)B_ * SPLITS * NSEQ * D_);   // 16.3 MB (f16 Opart)
  float*    gsum = (float*)alloc(1024);
  float*    gsq  = (float*)alloc(1024);

  float* Mp = (float*)xpT2;                 // xpT2 dead after qkv_k
  float* Lp = Mp + (size_t)B_ * SPLITS * NSEQ;
  unsigned* outp = (unsigned*)Kv;           // Kv+Vt dead after flash_k (8.26 MB >= 8.13)

  const float* xin = (const float*)d_in[0];
  pool_k<<<dim3(63, 5, B_), 256, 0, stream>>>(xin, xp, xpT2, W2,
                                              (const float*)d_in[1], (const float*)d_in[2],
                                              (const float*)d_in[3], gsum, gsq);
  qkv_k<<<dim3(1536), 256, 0, stream>>>(xpT2, W2, Qh, Ql, Kv, Vt);
  flash_k<<<dim3(1024), 256, 0, stream>>>(Qh, Ql, Kv, Vt, big, Mp, Lp);
  out_k<<<dim3(1024), 256, 0, stream>>>(big, Mp, Lp, (const float*)d_in[4], outp, gsum, gsq);
  bn_k<<<(TOT + 255) / 256, 256, 0, stream>>>(outp, gsum, gsq,
                                              (const float*)d_in[5], (const float*)d_in[6],
                                              xp, (float*)d_out);
}

// Round 16
// 269.313 us; speedup vs baseline: 1.0612x; 1.0612x over previous
//
#include <hip/hip_runtime.h>

#define B_   4
#define C_   256
#define C2_  128
#define HIN  128
#define HO   63
#define NSEQ 3969          // 63*63
#define NPAD 4032          // 63*64
#define QPAD 4096
#define D_   128
#define TOT  (B_*C_*NSEQ)  // 4064256
#define SPLITS 4

typedef _Float16 f16x8 __attribute__((ext_vector_type(8)));
typedef _Float16 f16x2 __attribute__((ext_vector_type(2)));
typedef short    s16x8 __attribute__((ext_vector_type(8)));
typedef float    f32x4 __attribute__((ext_vector_type(4)));
typedef unsigned short u16;
typedef u16 u16x8 __attribute__((ext_vector_type(8)));
typedef unsigned u32x2 __attribute__((ext_vector_type(2)));
typedef unsigned u32x4 __attribute__((ext_vector_type(4)));

#define MFMA16(a,b,c) __builtin_amdgcn_mfma_f32_16x16x32_f16((a),(b),(c),0,0,0)
#define MFMABF(a,b,c) __builtin_amdgcn_mfma_f32_16x16x32_bf16((a),(b),(c),0,0,0)

__device__ __forceinline__ float b2f(u16 u) {
  unsigned v = ((unsigned)u) << 16;
  return __builtin_bit_cast(float, v);
}
__device__ __forceinline__ u16 f2b(float f) {   // RTN-even
  unsigned u = __builtin_bit_cast(unsigned, f);
  return (u16)((u + 0x7FFFu + ((u >> 16) & 1u)) >> 16);
}
__device__ __forceinline__ float h2f(u16 u) {   // f16 bits -> float
  return (float)__builtin_bit_cast(_Float16, u);
}
__device__ __forceinline__ unsigned packhl(float v) {  // f16 hi/lo split -> u32
  _Float16 hx = (_Float16)v;
  _Float16 lx = (_Float16)(v - (float)hx);
  return (unsigned)__builtin_bit_cast(u16, hx) |
         ((unsigned)__builtin_bit_cast(u16, lx) << 16);
}

template<int CTRL>
__device__ __forceinline__ float dppf(float x) {
  return __builtin_bit_cast(float,
      __builtin_amdgcn_mov_dpp(__builtin_bit_cast(int, x), CTRL, 0xF, 0xF, true));
}
__device__ __forceinline__ float rmax16(float x) {
  x = fmaxf(x, dppf<0xB1>(x));
  x = fmaxf(x, dppf<0x4E>(x));
  x = fmaxf(x, dppf<0x124>(x));
  x = fmaxf(x, dppf<0x128>(x));
  return x;
}
__device__ __forceinline__ float rsum16(float x) {
  x += dppf<0xB1>(x);
  x += dppf<0x4E>(x);
  x += dppf<0x124>(x);
  x += dppf<0x128>(x);
  return x;
}

// ========== pool_k: maxpool 3x3/s2 + transpose + bf16 hi/lo split ==========
// xp stored f16 (residual only; values <= ~5, err ~2^-11 rel)
__global__ __launch_bounds__(256) void pool_k(
    const float* __restrict__ x, _Float16* __restrict__ xp, u16* __restrict__ xpT2,
    u16* __restrict__ W2, const float* __restrict__ tw, const float* __restrict__ pw,
    const float* __restrict__ gw, float* gsum, float* gsq) {
  __shared__ unsigned Tls[64 * 69];
  int h = blockIdx.x, cg = blockIdx.y, b = blockIdx.z;
  int tid = threadIdx.x;
  if (cg == 4) {                       // weight split (252 blocks, need 192)
    if (h == 0 && b == 0) { gsum[tid] = 0.f; gsq[tid] = 0.f; }
    int base = ((b * 63 + h) * 256 + tid) * 2;
#pragma unroll
    for (int e2 = 0; e2 < 2; e2++) {
      int e = base + e2;
      if (e < 3 * 128 * 256) {
        int mat = e >> 15, idx = e & 32767;
        int oc = idx >> 8, k = idx & 255;
        const float* W = (mat == 0) ? tw : (mat == 1) ? pw : gw;
        float v = W[oc * 256 + k];
        u16 hi = f2b(v);
        u16 lo = f2b(v - b2f(hi));
        W2[((long)(mat * 128 + oc)) * 512 + 2 * k]     = hi;
        W2[((long)(mat * 128 + oc)) * 512 + 2 * k + 1] = lo;
      }
    }
    return;
  }
  int cl = tid >> 2, w0 = (tid & 3) << 4;   // 64 channels x 4 w-groups of 16
  int c = cg * 64 + cl;
  long rowbase = ((long)(b * C_ + c) * HIN + 2 * h) * HIN + 2 * w0;
  float best[16];
#pragma unroll
  for (int j = 0; j < 16; j++) best[j] = -3e38f;
#pragma unroll
  for (int dh = 0; dh < 3; dh++) {
    long ro = rowbase + dh * HIN;
    float v[40];
#pragma unroll
    for (int ch = 0; ch < 10; ch++) {
      f32x4 a = *(const f32x4*)(x + ro + ch * 4);
#pragma unroll
      for (int j = 0; j < 4; j++) v[ch * 4 + j] = a[j];
    }
#pragma unroll
    for (int j = 0; j < 16; j++)
      best[j] = fmaxf(best[j], fmaxf(fmaxf(v[2 * j], v[2 * j + 1]), v[2 * j + 2]));
  }
  long xo = (long)(b * C_ + c) * NPAD + h * HO + w0;
#pragma unroll
  for (int j = 0; j < 16; j++)
    if (w0 + j < HO) xp[xo + j] = (_Float16)best[j];
#pragma unroll
  for (int j = 0; j < 16; j++) {
    u16 hi = f2b(best[j]);
    u16 lo = f2b(best[j] - b2f(hi));
    Tls[cl * 69 + w0 + j] = (unsigned)hi | ((unsigned)lo << 16);
  }
  __syncthreads();
  int w = tid >> 2, cc0 = (tid & 3) << 4;   // 64 w x 4 c-groups of 16
  if (w < HO) {
    int p = h * HO + w;
    u16 outv[32];
#pragma unroll
    for (int j = 0; j < 16; j++) {
      unsigned word = Tls[(cc0 + j) * 69 + w];
      outv[2 * j]     = (u16)(word & 0xFFFF);
      outv[2 * j + 1] = (u16)(word >> 16);
    }
    u16* d = xpT2 + ((long)b * NPAD + p) * 512 + 2 * (cg * 64 + cc0);
#pragma unroll
    for (int q = 0; q < 4; q++)
      *(u16x8*)(d + q * 8) = *(u16x8*)&outv[q * 8];
  }
}

// ========== qkv_k: K=512 bf16-split MFMA GEMM, XCD-grouped blocks ==========
__global__ __launch_bounds__(256) void qkv_k(
    const u16* __restrict__ xpT2, const u16* __restrict__ W2,
    _Float16* Qh, _Float16* Ql, _Float16* Kv, _Float16* Vt) {
  __shared__ u16 Asm[64 * 256];       // 32 KB, XOR-swizzled 16B chunks
  __shared__ u16 Bsm[64 * 256];       // 32 KB
  __shared__ float Tsm[4][16][64];    // 16 KB
  int x = blockIdx.x;
  int y = (x % 48) >> 3;              // 0..5
  int g = (x & 7) + ((x / 48) << 3);  // (pt,b) group, same-XCD for all y
  if (g >= 252) return;
  int pt = g % 63, b = g / 63;
  int tid = threadIdx.x, wave = tid >> 6, lane = tid & 63;
  int quad = lane >> 4, l16 = lane & 15;
  int mat = y >> 1, half = y & 1;
  const u16* Wr = W2 + ((long)(mat * 128 + half * 64)) * 512;
  const u16* Xb = xpT2 + ((long)b * NPAD + pt * 64) * 512;
  f32x4 acc[4];
#pragma unroll
  for (int s = 0; s < 4; s++) acc[s] = (f32x4){0.f, 0.f, 0.f, 0.f};
#pragma unroll
  for (int ck = 0; ck < 2; ck++) {    // two 256-wide K chunks of 512
    if (ck) __syncthreads();
#pragma unroll
    for (int i = 0; i < 8; i++) {
      int g2 = tid + i * 256;         // 0..2047
      int r = g2 >> 5, ccc = g2 & 31;
      int sw = (ccc ^ (r & 15)) << 3;
      *(u16x8*)&Asm[r * 256 + sw] = *(const u16x8*)(Wr + (long)r * 512 + ck * 256 + ccc * 8);
      *(u16x8*)&Bsm[r * 256 + sw] = *(const u16x8*)(Xb + (long)r * 512 + ck * 256 + ccc * 8);
    }
    __syncthreads();
#pragma unroll
    for (int kc = 0; kc < 8; kc++) {
      s16x8 a = *(const s16x8*)&Asm[(wave * 16 + l16) * 256 + (((kc * 4 + quad) ^ l16) << 3)];
#pragma unroll
      for (int s = 0; s < 4; s++) {
        s16x8 bv = *(const s16x8*)&Bsm[(s * 16 + l16) * 256 + (((kc * 4 + quad) ^ l16) << 3)];
        acc[s] = MFMABF(a, bv, acc[s]);
      }
    }
  }
  int chanb = half * 64 + wave * 16;
  if (mat == 2) {
    _Float16* dv = Vt + (long)b * C2_ * NPAD;
#pragma unroll
    for (int s = 0; s < 4; s++)
#pragma unroll
      for (int r = 0; r < 4; r++) {
        int p = pt * 64 + s * 16 + l16;
        if (p < NSEQ) dv[(long)(chanb + quad * 4 + r) * NPAD + p] = (_Float16)acc[s][r];
      }
  } else {
#pragma unroll
    for (int s = 0; s < 4; s++)
#pragma unroll
      for (int r = 0; r < 4; r++)
        Tsm[wave][quad * 4 + r][s * 16 + l16] = acc[s][r];
    int p = pt * 64 + lane;           // wave-local LDS roundtrip, no barrier
    if (p < NSEQ) {
      f16x8 hv[2], lv[2];
#pragma unroll
      for (int cl2 = 0; cl2 < 16; cl2++) {
        float v = Tsm[wave][cl2][lane];
        _Float16 hx = (_Float16)v;
        hv[cl2 >> 3][cl2 & 7] = hx;
        lv[cl2 >> 3][cl2 & 7] = (_Float16)(v - (float)hx);
      }
      if (mat == 0) {
        _Float16* dh = Qh + ((long)b * QPAD + p) * 128 + chanb;
        _Float16* dl = Ql + ((long)b * QPAD + p) * 128 + chanb;
        *(f16x8*)dh = hv[0]; *(f16x8*)(dh + 8) = hv[1];
        *(f16x8*)dl = lv[0]; *(f16x8*)(dl + 8) = lv[1];
      } else {
        _Float16* dk = Kv + ((long)b * NPAD + p) * 128 + chanb;
        *(f16x8*)dk = hv[0]; *(f16x8*)(dk + 8) = hv[1];
      }
    }
  }
}

// ========== flash v14 (R14-proven): XCD-grouped splits, f16 Opart ==========
__global__ __launch_bounds__(256, 3) void flash_k(
    const _Float16* __restrict__ Qh, const _Float16* __restrict__ Ql,
    const _Float16* __restrict__ Kv, const _Float16* __restrict__ Vt,
    _Float16* __restrict__ Opart, float* __restrict__ Mp, float* __restrict__ Lp) {
  __shared__ _Float16 Ks[64 * 128];   // 16 KB
  __shared__ _Float16 Vs[128 * 64];   // 16 KB
  __shared__ _Float16 Ps[4 * 640];    // 5 KB: per-wave 16x40-padded half-tile
  int x = blockIdx.x;
  int split = (x % 32) >> 3;          // 0..3
  int g = (x & 7) + ((x / 32) << 3);  // (qt,b) group, same-XCD for all splits
  if (g >= 252) return;
  int qt = g % 63, b = g / 63;
  int tid = threadIdx.x, wave = tid >> 6, lane = tid & 63;
  int quad = lane >> 4, l16 = lane & 15;
  const _Float16* Qhb = Qh + (long)b * QPAD * D_;
  const _Float16* Qlb = Ql + (long)b * QPAD * D_;
  const _Float16* Kb  = Kv + (long)b * NPAD * D_;
  const _Float16* Vb  = Vt + (long)b * C2_ * NPAD;

  long qrow = qt * 64 + wave * 16 + l16;
  f16x8 aqh[4], aql[4];
#pragma unroll
  for (int kk = 0; kk < 4; kk++) {
    aqh[kk] = *(const f16x8*)(Qhb + qrow * D_ + kk * 32 + quad * 8);
    aql[kk] = *(const f16x8*)(Qlb + qrow * D_ + kk * 32 + quad * 8);
  }
  f32x4 o_acc[8];
#pragma unroll
  for (int s = 0; s < 8; s++) o_acc[s] = (f32x4){0.f, 0.f, 0.f, 0.f};
  float m_r[4] = {-3e38f, -3e38f, -3e38f, -3e38f};
  float l_r[4] = {0.f, 0.f, 0.f, 0.f};
  const float LOG2E = 1.4426950408889634f;
  int po = wave * 640;
  int t0 = split * 16;
  int t1 = (t0 + 16 < 63) ? (t0 + 16) : 63;   // splits: 16,16,16,15

  int rK = tid >> 4, qK = tid & 15;
  int cV = tid >> 3, qV = tid & 7;
  const _Float16* Kg = Kb + rK * D_ + qK * 8;              // + t*8192 + i*2048
  const _Float16* Vg = Vb + (long)cV * NPAD + qV * 8;      // + t*64 + i*32*NPAD
  int lk = rK * 128 + ((qK ^ (rK & 15)) << 3);             // + i*2048
  int lv = cV * 64 + ((qV ^ (cV & 7)) << 3);               // + i*2048

  f16x8 pk0, pk1, pk2, pk3, pv0, pv1, pv2, pv3;
  {
    long ko = (long)t0 * 8192;
    pk0 = *(const f16x8*)(Kg + ko);
    pk1 = *(const f16x8*)(Kg + ko + 2048);
    pk2 = *(const f16x8*)(Kg + ko + 4096);
    pk3 = *(const f16x8*)(Kg + ko + 6144);
    int vo = t0 * 64;
    pv0 = *(const f16x8*)(Vg + vo);
    pv1 = *(const f16x8*)(Vg + vo + (long)32 * NPAD);
    pv2 = *(const f16x8*)(Vg + vo + (long)64 * NPAD);
    pv3 = *(const f16x8*)(Vg + vo + (long)96 * NPAD);
  }

#pragma unroll 1
  for (int t = t0; t < t1; t++) {
    __syncthreads();                  // (A) prior tile's Ks/Vs reads done
    *(f16x8*)&Ks[lk]        = pk0;
    *(f16x8*)&Ks[lk + 2048] = pk1;
    *(f16x8*)&Ks[lk + 4096] = pk2;
    *(f16x8*)&Ks[lk + 6144] = pk3;
    *(f16x8*)&Vs[lv]        = pv0;
    *(f16x8*)&Vs[lv + 2048] = pv1;
    *(f16x8*)&Vs[lv + 4096] = pv2;
    *(f16x8*)&Vs[lv + 6144] = pv3;
    __syncthreads();                  // (B) tiles visible
    if (t + 1 < t1) {                 // issue next tile a full phase early
      long ko = (long)(t + 1) * 8192;
      pk0 = *(const f16x8*)(Kg + ko);
      pk1 = *(const f16x8*)(Kg + ko + 2048);
      pk2 = *(const f16x8*)(Kg + ko + 4096);
      pk3 = *(const f16x8*)(Kg + ko + 6144);
      int vo = (t + 1) * 64;
      pv0 = *(const f16x8*)(Vg + vo);
      pv1 = *(const f16x8*)(Vg + vo + (long)32 * NPAD);
      pv2 = *(const f16x8*)(Vg + vo + (long)64 * NPAD);
      pv3 = *(const f16x8*)(Vg + vo + (long)96 * NPAD);
    }

    f32x4 s_acc[4];
#pragma unroll
    for (int s = 0; s < 4; s++) s_acc[s] = (f32x4){0.f, 0.f, 0.f, 0.f};
    __builtin_amdgcn_s_setprio(1);
#pragma unroll
    for (int kk = 0; kk < 4; kk++) {
      f16x8 bh[4];
#pragma unroll
      for (int s = 0; s < 4; s++)
        bh[s] = *(const f16x8*)&Ks[(s * 16 + l16) * 128 + (((kk * 4 + quad) ^ l16) << 3)];
#pragma unroll
      for (int s = 0; s < 4; s++) s_acc[s] = MFMA16(aqh[kk], bh[s], s_acc[s]);
#pragma unroll
      for (int s = 0; s < 4; s++) s_acc[s] = MFMA16(aql[kk], bh[s], s_acc[s]);
    }
    __builtin_amdgcn_s_setprio(0);

    if (t == 62) {                    // only the last K-tile has invalid cols
#pragma unroll
      for (int s = 0; s < 4; s++) {
        if (t * 64 + s * 16 + l16 >= NSEQ) {
#pragma unroll
          for (int r = 0; r < 4; r++) s_acc[s][r] = -3e38f;
        }
      }
    }
    float mx[4];
#pragma unroll
    for (int r = 0; r < 4; r++) {
      mx[r] = fmaxf(fmaxf(s_acc[0][r], s_acc[1][r]), fmaxf(s_acc[2][r], s_acc[3][r]));
      mx[r] = rmax16(mx[r]);
    }
    // defer-max: only rescale when the running max grows by >8
    bool need = false;
#pragma unroll
    for (int r = 0; r < 4; r++) need = need || (mx[r] > m_r[r] + 8.0f);
    if (__any(need)) {
      float alpha[4];
#pragma unroll
      for (int r = 0; r < 4; r++) {
        float mn = fmaxf(m_r[r], mx[r]);
        alpha[r] = exp2f((m_r[r] - mn) * LOG2E);
        m_r[r] = mn;
        l_r[r] *= alpha[r];
      }
#pragma unroll
      for (int s8 = 0; s8 < 8; s8++)
#pragma unroll
        for (int r = 0; r < 4; r++) o_acc[s8][r] *= alpha[r];
    }
    float rs[4] = {0.f, 0.f, 0.f, 0.f};
    // phase A: P k-cols 0..31 (s=0,1) -> padded half-buffer [q=m][k]
#pragma unroll
    for (int s = 0; s < 2; s++)
#pragma unroll
      for (int r = 0; r < 4; r++) {
        float p = exp2f((s_acc[s][r] - m_r[r]) * LOG2E);
        rs[r] += p;
        int m = quad * 4 + r;
        Ps[po + m * 40 + s * 16 + l16] = (_Float16)p;
      }
    f16x8 ap0 = *(const f16x8*)&Ps[po + l16 * 40 + quad * 8];
    // phase B: P k-cols 32..63 overwrite same region (in-wave DS order)
#pragma unroll
    for (int s = 2; s < 4; s++)
#pragma unroll
      for (int r = 0; r < 4; r++) {
        float p = exp2f((s_acc[s][r] - m_r[r]) * LOG2E);
        rs[r] += p;
        int m = quad * 4 + r;
        Ps[po + m * 40 + (s - 2) * 16 + l16] = (_Float16)p;
      }
    f16x8 ap1 = *(const f16x8*)&Ps[po + l16 * 40 + quad * 8];
#pragma unroll
    for (int r = 0; r < 4; r++) {
      rs[r] = rsum16(rs[r]);
      l_r[r] += rs[r];
    }
    __builtin_amdgcn_s_setprio(1);
#pragma unroll
    for (int s8 = 0; s8 < 8; s8++) {
      int c2 = s8 * 16 + l16;
      f16x8 bv = *(const f16x8*)&Vs[c2 * 64 + ((quad ^ (c2 & 7)) << 3)];
      o_acc[s8] = MFMA16(ap0, bv, o_acc[s8]);
    }
#pragma unroll
    for (int s8 = 0; s8 < 8; s8++) {
      int c2 = s8 * 16 + l16;
      f16x8 bv = *(const f16x8*)&Vs[c2 * 64 + (((4 + quad) ^ (c2 & 7)) << 3)];
      o_acc[s8] = MFMA16(ap1, bv, o_acc[s8]);
    }
    __builtin_amdgcn_s_setprio(0);
  }

  _Float16* Ob = Opart + (long)(b * SPLITS + split) * NSEQ * D_;
  float* Mb = Mp + (long)(b * SPLITS + split) * NSEQ;
  float* Lb = Lp + (long)(b * SPLITS + split) * NSEQ;
#pragma unroll
  for (int r = 0; r < 4; r++) {
    int n = qt * 64 + wave * 16 + quad * 4 + r;
    if (n < NSEQ) {
#pragma unroll
      for (int s8 = 0; s8 < 8; s8++)
        Ob[(long)n * D_ + s8 * 16 + l16] = (_Float16)o_acc[s8][r];
      if (l16 == 0) { Mb[n] = m_r[r]; Lb[n] = l_r[r]; }
    }
  }
}

// ========== merge split partials (f16 Opart) -> packed f16 hi/lo y ==========
__global__ __launch_bounds__(256) void merge_k(const _Float16* __restrict__ Opart,
                                               const float* __restrict__ Mp,
                                               const float* __restrict__ Lp,
                                               unsigned* __restrict__ Yhl) {
  int row = blockIdx.x * 4 + (threadIdx.x >> 6);
  int lane = threadIdx.x & 63;
  int b = row / NSEQ, n = row - b * NSEQ;
  const float LOG2E = 1.4426950408889634f;
  float ms[SPLITS], m = -3e38f;
#pragma unroll
  for (int s = 0; s < SPLITS; s++) {
    ms[s] = Mp[(long)(b * SPLITS + s) * NSEQ + n];
    m = fmaxf(m, ms[s]);
  }
  float den = 0.f, a0 = 0.f, a1 = 0.f;
  int d = lane * 2;
#pragma unroll
  for (int s = 0; s < SPLITS; s++) {
    float w = exp2f((ms[s] - m) * LOG2E);
    den += Lp[(long)(b * SPLITS + s) * NSEQ + n] * w;
    f16x2 o2 = *(const f16x2*)(Opart + ((long)(b * SPLITS + s) * NSEQ + n) * D_ + d);
    a0 += w * (float)o2[0];
    a1 += w * (float)o2[1];
  }
  float inv = 1.f / den;
  u32x2 wv;
  wv[0] = packhl(a0 * inv);
  wv[1] = packhl(a1 * inv);
  *(u32x2*)(Yhl + ((long)b * NSEQ + n) * D_ + d) = wv;
}

// ========== out_k v5: y_w MFMA GEMM on packed raw-viewed y + BN stats,
// XCD-grouped; writes packed f16 hi/lo outp ==========
__global__ __launch_bounds__(256) void out_k(const unsigned* __restrict__ Yhl,
                                             const float* __restrict__ yw,
                                             unsigned* __restrict__ outp,
                                             float* gsum, float* gsumsq) {
  __shared__ u16 Asm2[64 * 256];   // w tile, rows c_out, k-interleaved hi/lo
  __shared__ u16 Bsm2[64 * 256];   // y tile, rows p, k-interleaved hi/lo
  int x = blockIdx.x;
  int ct = (x % 32) >> 3;             // 0..3
  int g = (x & 7) + ((x / 32) << 3);
  if (g >= 252) return;
  int pt = g % 63, b = g / 63;
  int tid = threadIdx.x, wave = tid >> 6, lane = tid & 63;
  int quad = lane >> 4, l16 = lane & 15;
  const unsigned* Yb = Yhl + (long)b * NSEQ * D_;
  int p0 = pt * 64;
#pragma unroll
  for (int i = 0; i < 8; i++) {
    int g2 = tid + i * 256;
    // W: r = c_out row (0..63), ccc = 4-float chunk (0..31)
    int r = g2 >> 5, ccc = g2 & 31;
    f32x4 w4 = *(const f32x4*)(yw + (ct * 64 + r) * C2_ + ccc * 4);
    u16 tw2[8];
#pragma unroll
    for (int j = 0; j < 4; j++) {
      unsigned wp = packhl(w4[j]);
      tw2[2 * j]     = (u16)(wp & 0xFFFF);
      tw2[2 * j + 1] = (u16)(wp >> 16);
    }
    *(u16x8*)&Asm2[r * 256 + ((ccc ^ (r & 15)) << 3)] = *(u16x8*)tw2;
    // Y (raw view): element (c2, p) = flat y[c2*NSEQ + p], already hi/lo packed
    int p = g2 & 63, c4 = g2 >> 6;
    u16 ty[8];
    bool ok = (p0 + p) < NSEQ;
#pragma unroll
    for (int j = 0; j < 4; j++) {
      int c2 = c4 * 4 + j;
      unsigned w = ok ? Yb[(long)c2 * NSEQ + p0 + p] : 0u;
      ty[2 * j]     = (u16)(w & 0xFFFF);
      ty[2 * j + 1] = (u16)(w >> 16);
    }
    *(u16x8*)&Bsm2[p * 256 + ((c4 ^ (p & 15)) << 3)] = *(u16x8*)ty;
  }
  __syncthreads();
  f32x4 acc[4];
#pragma unroll
  for (int s = 0; s < 4; s++) acc[s] = (f32x4){0.f, 0.f, 0.f, 0.f};
#pragma unroll
  for (int kc = 0; kc < 8; kc++) {
    f16x8 a = *(const f16x8*)&Asm2[(wave * 16 + l16) * 256 + (((kc * 4 + quad) ^ l16) << 3)];
#pragma unroll
    for (int s = 0; s < 4; s++) {
      f16x8 bv = *(const f16x8*)&Bsm2[(s * 16 + l16) * 256 + (((kc * 4 + quad) ^ l16) << 3)];
      acc[s] = MFMA16(a, bv, acc[s]);
    }
  }
  long ob = ((long)b * C_ + ct * 64 + wave * 16) * NSEQ;
#pragma unroll
  for (int r = 0; r < 4; r++) {
    int row = quad * 4 + r;
    float s1 = 0.f, s2 = 0.f;
#pragma unroll
    for (int s = 0; s < 4; s++) {
      int p = p0 + s * 16 + l16;
      float v = acc[s][r];
      if (p < NSEQ) {
        outp[ob + (long)row * NSEQ + p] = packhl(v);
        s1 += v;
        s2 += v * v;
      }
    }
    s1 = rsum16(s1);
    s2 = rsum16(s2);
    if (l16 == 0) {
      atomicAdd(gsum + ct * 64 + wave * 16 + row, s1);
      atomicAdd(gsumsq + ct * 64 + wave * 16 + row, s2);
    }
  }
}

// ========== BN (training) + residual + relu, x4 vectorized ==========
__global__ __launch_bounds__(256) void bn_k(const unsigned* __restrict__ outp,
                                            const float* gsum, const float* gsumsq,
                                            const float* __restrict__ bnw,
                                            const float* __restrict__ bnb,
                                            const _Float16* __restrict__ xp, float* out) {
  int base = (blockIdx.x * 256 + threadIdx.x) * 4;
  if (base >= TOT) return;
  const float invn = 1.0f / (float)(B_ * NSEQ);
  int p = base % NSEQ;
  int bc = base / NSEQ;
  if (p + 3 < NSEQ) {                 // fast path: all 4 in one (b,c) row
    int c = bc & (C_ - 1);
    float mean = gsum[c] * invn;
    float var = gsumsq[c] * invn - mean * mean;
    var = fmaxf(var, 0.f);
    float is = rsqrtf(var + 1e-5f) * bnw[c];
    float bb = bnb[c];
    u32x4 w4 = *(const u32x4*)(outp + base);
    const _Float16* xr = xp + (long)bc * NPAD + p;
    f32x4 o;
#pragma unroll
    for (int j = 0; j < 4; j++) {
      float ov = h2f((u16)(w4[j] & 0xFFFF)) + h2f((u16)(w4[j] >> 16));
      float v = (ov - mean) * is + bb + (float)xr[j];
      o[j] = fmaxf(v, 0.f);
    }
    *(f32x4*)(out + base) = o;
  } else {                            // row-boundary tail (rare)
#pragma unroll
    for (int j = 0; j < 4; j++) {
      int idx = base + j;
      if (idx >= TOT) break;
      int pp = idx % NSEQ;
      int bcc = idx / NSEQ;
      int c = bcc & (C_ - 1);
      float mean = gsum[c] * invn;
      float var = gsumsq[c] * invn - mean * mean;
      var = fmaxf(var, 0.f);
      float is = rsqrtf(var + 1e-5f);
      unsigned w = outp[idx];
      float ov = h2f((u16)(w & 0xFFFF)) + h2f((u16)(w >> 16));
      float v = (ov - mean) * is * bnw[c] + bnb[c] + (float)xp[(long)bcc * NPAD + pp];
      out[idx] = fmaxf(v, 0.f);
    }
  }
}

// ========== launcher (6 graph nodes) ==========
extern "C" void kernel_launch(void* const* d_in, const int* in_sizes, int n_in,
                              void* d_out, int out_size, void* d_ws, size_t ws_size,
                              hipStream_t stream) {
  size_t off = 0;
  auto alloc = [&](size_t bytes) -> char* {
    char* p = (char*)d_ws + off;
    off += (bytes + 255) & ~(size_t)255;
    return p;
  };
  _Float16* xp   = (_Float16*)alloc(2 * (size_t)B_ * C_ * NPAD);            // 8.25 MB (f16)
  u16*      xpT2 = (u16*)alloc(2 * (size_t)B_ * NPAD * 512);                // 16.5 MB (Mp/Lp later)
  u16*      W2   = (u16*)alloc(2 * (size_t)3 * 128 * 512);                  // 384 KB
  _Float16* Qh   = (_Float16*)alloc(2 * (size_t)B_ * QPAD * D_);            // 4.2 MB (Yhl later)
  _Float16* Ql   = (_Float16*)alloc(2 * (size_t)B_ * QPAD * D_);            // 4.2 MB
  _Float16* Kv   = (_Float16*)alloc(2 * (size_t)B_ * NPAD * D_);            // 4.1 MB (outp later)
  _Float16* Vt   = (_Float16*)alloc(2 * (size_t)B_ * C2_ * NPAD);           // 4.1 MB
  _Float16* big  = (_Float16*)alloc(2 * (size_t)B_ * SPLITS * NSEQ * D_);   // 16.3 MB (f16 Opart)
  float*    gsum = (float*)alloc(1024);
  float*    gsq  = (float*)alloc(1024);

  float* Mp = (float*)xpT2;                 // xpT2 dead after qkv_k
  float* Lp = Mp + (size_t)B_ * SPLITS * NSEQ;
  unsigned* Yhl  = (unsigned*)Qh;           // Qh+Ql dead after flash_k (8.39 MB >= 8.13)
  unsigned* outp = (unsigned*)Kv;           // Kv+Vt dead after flash_k (8.26 MB >= 8.13)

  const float* xin = (const float*)d_in[0];
  pool_k<<<dim3(63, 5, B_), 256, 0, stream>>>(xin, xp, xpT2, W2,
                                              (const float*)d_in[1], (const float*)d_in[2],
                                              (const float*)d_in[3], gsum, gsq);
  qkv_k<<<dim3(1536), 256, 0, stream>>>(xpT2, W2, Qh, Ql, Kv, Vt);
  flash_k<<<dim3(1024), 256, 0, stream>>>(Qh, Ql, Kv, Vt, big, Mp, Lp);
  merge_k<<<3969, 256, 0, stream>>>(big, Mp, Lp, Yhl);
  out_k<<<dim3(1024), 256, 0, stream>>>(Yhl, (const float*)d_in[4], outp, gsum, gsq);
  bn_k<<<(TOT / 4 + 255) / 256, 256, 0, stream>>>(outp, gsum, gsq,
                                                  (const float*)d_in[5], (const float*)d_in[6],
                                                  xp, (float*)d_out);
}